// Round 7
// baseline (309.589 us; speedup 1.0000x reference)
//
#include <hip/hip_runtime.h>

#define D 64

// --- degree histogram over dst, dst-sliced for XCD-local atomics -----------
__global__ void count_deg_sliced_kernel(const int* __restrict__ dst, int* __restrict__ deg,
                                        int nE, int slice_size) {
    const int g  = blockIdx.x & 7;    // slice id == XCD id (perf heuristic)
    const int gb = blockIdx.x >> 3;
    const int lo = g * slice_size;
    const int hi = lo + slice_size;
    int e4 = (gb * 256 + (int)threadIdx.x) * 4;
    if (e4 + 3 < nE) {
        int4 d = *(const int4*)(dst + e4);
        if (d.x >= lo && d.x < hi) atomicAdd(&deg[d.x], 1);
        if (d.y >= lo && d.y < hi) atomicAdd(&deg[d.y], 1);
        if (d.z >= lo && d.z < hi) atomicAdd(&deg[d.z], 1);
        if (d.w >= lo && d.w < hi) atomicAdd(&deg[d.w], 1);
    } else if (e4 < nE) {
        for (int e = e4; e < nE; ++e) {
            int dd = dst[e];
            if (dd >= lo && dd < hi) atomicAdd(&deg[dd], 1);
        }
    }
}

// --- hierarchical exclusive scan: A (per-block tile scan) ------------------
__global__ __launch_bounds__(256) void scan_a_kernel(const int* __restrict__ deg,
                                                     int* __restrict__ row_ptr,
                                                     int* __restrict__ blocksums, int N) {
    __shared__ int s[256];
    int t = threadIdx.x;
    int i = blockIdx.x * 256 + t;
    int v = (i < N) ? deg[i] : 0;
    s[t] = v;
    __syncthreads();
    #pragma unroll
    for (int d = 1; d < 256; d <<= 1) {
        int u = (t >= d) ? s[t - d] : 0;
        __syncthreads();
        s[t] += u;
        __syncthreads();
    }
    if (i < N) row_ptr[i] = s[t] - v;             // exclusive (block-local)
    if (t == 255) blocksums[blockIdx.x] = s[255]; // block total
}

// --- B: single-block exclusive scan of block sums (nb <= 256) --------------
__global__ __launch_bounds__(256) void scan_b_kernel(int* __restrict__ blocksums,
                                                     int* __restrict__ row_ptr,
                                                     int nb, int N) {
    __shared__ int s[256];
    int t = threadIdx.x;
    int v = (t < nb) ? blocksums[t] : 0;
    s[t] = v;
    __syncthreads();
    #pragma unroll
    for (int d = 1; d < 256; d <<= 1) {
        int u = (t >= d) ? s[t - d] : 0;
        __syncthreads();
        s[t] += u;
        __syncthreads();
    }
    if (t < nb) blocksums[t] = s[t] - v;  // exclusive block offsets
    if (t == 255) row_ptr[N] = s[255];    // total = E
}

// --- C: apply block offsets, emit final row_ptr + cursor -------------------
__global__ __launch_bounds__(256) void scan_c_kernel(int* __restrict__ row_ptr,
                                                     int* __restrict__ cursor,
                                                     const int* __restrict__ blocksums, int N) {
    int i = blockIdx.x * 256 + threadIdx.x;
    if (i < N) {
        int r = row_ptr[i] + blocksums[blockIdx.x];
        row_ptr[i] = r;
        cursor[i] = r;
    }
}

// --- bucket edges by dst: col[pos] = src, dst-sliced for XCD locality ------
__global__ __launch_bounds__(256) void fill_csr_sliced_kernel(
    const int* __restrict__ src, const int* __restrict__ dst,
    int* __restrict__ cursor, int* __restrict__ col,
    int nE, int slice_size)
{
    const int g  = blockIdx.x & 7;    // slice id == XCD id (perf heuristic)
    const int gb = blockIdx.x >> 3;   // block index within group
    const int lo = g * slice_size;
    const int hi = lo + slice_size;
    int e4 = (gb * 256 + (int)threadIdx.x) * 4;
    if (e4 + 3 < nE) {
        int4 d = *(const int4*)(dst + e4);
        bool m0 = (d.x >= lo) & (d.x < hi);
        bool m1 = (d.y >= lo) & (d.y < hi);
        bool m2 = (d.z >= lo) & (d.z < hi);
        bool m3 = (d.w >= lo) & (d.w < hi);
        if (m0 | m1 | m2 | m3) {
            int4 s = *(const int4*)(src + e4);
            if (m0) col[atomicAdd(&cursor[d.x], 1)] = s.x;
            if (m1) col[atomicAdd(&cursor[d.y], 1)] = s.y;
            if (m2) col[atomicAdd(&cursor[d.z], 1)] = s.z;
            if (m3) col[atomicAdd(&cursor[d.w], 1)] = s.w;
        }
    } else if (e4 < nE) {
        for (int e = e4; e < nE; ++e) {
            int dd = dst[e];
            if (dd >= lo && dd < hi) col[atomicAdd(&cursor[dd], 1)] = src[e];
        }
    }
}

// --- fused layer, TWO nodes per wave --------------------------------------
// out = relu?( ((sum_{s in N(i)} h[s] + h[i]) / (deg+1)) @ W + b )
// Wave = 16 lanes x float4 features, 4 edge-subgroups. Two independent gather
// chains (nodes iA, iB) double bytes-in-flight; epilogue shares one W-column
// load per k between both nodes' FMAs. Zero LDS, zero barriers.
__global__ __launch_bounds__(256, 4) void sage_layer_kernel(
    const float* __restrict__ h, const int* __restrict__ row_ptr,
    const int* __restrict__ col, const float* __restrict__ W,
    const float* __restrict__ bias, float* __restrict__ out,
    int N, int do_relu)
{
    const int lane = threadIdx.x & 63;
    const int sub  = lane >> 4;       // edge subgroup 0..3
    const int fq   = lane & 15;       // feature quad
    const int w    = threadIdx.x >> 6;
    const float bj = bias[lane];

    const float4* __restrict__ h4 = (const float4*)h;   // row i = h4[i*16+fq]
    const int nwaves = gridDim.x * 4;

    for (int p = (blockIdx.x * 4 + w) * 2; p < N; p += nwaves * 2) {
        const int iA = __builtin_amdgcn_readfirstlane(p);
        const int iB = iA + 1;                       // may be == N (guarded)
        const bool hasB = (iB < N);

        const int rsA = __builtin_amdgcn_readfirstlane(row_ptr[iA]);
        const int reA = __builtin_amdgcn_readfirstlane(row_ptr[iA + 1]);
        const int reB = hasB ? __builtin_amdgcn_readfirstlane(row_ptr[iB + 1]) : reA;
        const int rsB = reA;
        const int degA = reA - rsA;
        const int degB = reB - rsB;

        float4 aA0 = {0,0,0,0}, aA1 = {0,0,0,0}, aA2 = {0,0,0,0}, aA3 = {0,0,0,0};
        float4 aB0 = {0,0,0,0}, aB1 = {0,0,0,0}, aB2 = {0,0,0,0}, aB3 = {0,0,0,0};

        int eA = rsA, eB = rsB;
        while ((eA < reA) | (eB < reB)) {
            // issue both index loads first (independent chains)
            int idxA = 0, idxB = 0;
            if (eA < reA) { int ee = eA + lane; idxA = col[(ee < reA) ? ee : (reA - 1)]; }
            if (eB < reB) { int ee = eB + lane; idxB = col[(ee < reB) ? ee : (reB - 1)]; }

            if (eA < reA) {
                int rem = reA - eA;
                int steps = (((rem < 64) ? rem : 64) + 3) >> 2;
                int t = 0;
                for (; t + 4 <= steps; t += 4) {
                    int base = (t << 2) + sub;
                    int s0 = __shfl(idxA, base);
                    int s1 = __shfl(idxA, base + 4);
                    int s2 = __shfl(idxA, base + 8);
                    int s3 = __shfl(idxA, base + 12);
                    float4 v0 = h4[(size_t)s0 * 16 + fq];
                    float4 v1 = h4[(size_t)s1 * 16 + fq];
                    float4 v2 = h4[(size_t)s2 * 16 + fq];
                    float4 v3 = h4[(size_t)s3 * 16 + fq];
                    aA0.x += v0.x; aA0.y += v0.y; aA0.z += v0.z; aA0.w += v0.w;
                    aA1.x += v1.x; aA1.y += v1.y; aA1.z += v1.z; aA1.w += v1.w;
                    aA2.x += v2.x; aA2.y += v2.y; aA2.z += v2.z; aA2.w += v2.w;
                    aA3.x += v3.x; aA3.y += v3.y; aA3.z += v3.z; aA3.w += v3.w;
                }
                for (; t < steps; ++t) {
                    int s0 = __shfl(idxA, (t << 2) + sub);
                    float4 v0 = h4[(size_t)s0 * 16 + fq];
                    aA0.x += v0.x; aA0.y += v0.y; aA0.z += v0.z; aA0.w += v0.w;
                }
            }
            if (eB < reB) {
                int rem = reB - eB;
                int steps = (((rem < 64) ? rem : 64) + 3) >> 2;
                int t = 0;
                for (; t + 4 <= steps; t += 4) {
                    int base = (t << 2) + sub;
                    int s0 = __shfl(idxB, base);
                    int s1 = __shfl(idxB, base + 4);
                    int s2 = __shfl(idxB, base + 8);
                    int s3 = __shfl(idxB, base + 12);
                    float4 v0 = h4[(size_t)s0 * 16 + fq];
                    float4 v1 = h4[(size_t)s1 * 16 + fq];
                    float4 v2 = h4[(size_t)s2 * 16 + fq];
                    float4 v3 = h4[(size_t)s3 * 16 + fq];
                    aB0.x += v0.x; aB0.y += v0.y; aB0.z += v0.z; aB0.w += v0.w;
                    aB1.x += v1.x; aB1.y += v1.y; aB1.z += v1.z; aB1.w += v1.w;
                    aB2.x += v2.x; aB2.y += v2.y; aB2.z += v2.z; aB2.w += v2.w;
                    aB3.x += v3.x; aB3.y += v3.y; aB3.z += v3.z; aB3.w += v3.w;
                }
                for (; t < steps; ++t) {
                    int s0 = __shfl(idxB, (t << 2) + sub);
                    float4 v0 = h4[(size_t)s0 * 16 + fq];
                    aB0.x += v0.x; aB0.y += v0.y; aB0.z += v0.z; aB0.w += v0.w;
                }
            }
            eA += 64; eB += 64;
        }

        // combine + cross-subgroup reduce (lanes l, l^16, l^32, l^48)
        float4 tA, tB;
        tA.x = (aA0.x + aA1.x) + (aA2.x + aA3.x);
        tA.y = (aA0.y + aA1.y) + (aA2.y + aA3.y);
        tA.z = (aA0.z + aA1.z) + (aA2.z + aA3.z);
        tA.w = (aA0.w + aA1.w) + (aA2.w + aA3.w);
        tB.x = (aB0.x + aB1.x) + (aB2.x + aB3.x);
        tB.y = (aB0.y + aB1.y) + (aB2.y + aB3.y);
        tB.z = (aB0.z + aB1.z) + (aB2.z + aB3.z);
        tB.w = (aB0.w + aB1.w) + (aB2.w + aB3.w);
        tA.x += __shfl_xor(tA.x, 16); tA.x += __shfl_xor(tA.x, 32);
        tA.y += __shfl_xor(tA.y, 16); tA.y += __shfl_xor(tA.y, 32);
        tA.z += __shfl_xor(tA.z, 16); tA.z += __shfl_xor(tA.z, 32);
        tA.w += __shfl_xor(tA.w, 16); tA.w += __shfl_xor(tA.w, 32);
        tB.x += __shfl_xor(tB.x, 16); tB.x += __shfl_xor(tB.x, 32);
        tB.y += __shfl_xor(tB.y, 16); tB.y += __shfl_xor(tB.y, 32);
        tB.z += __shfl_xor(tB.z, 16); tB.z += __shfl_xor(tB.z, 32);
        tB.w += __shfl_xor(tB.w, 16); tB.w += __shfl_xor(tB.w, 32);

        // pad corrections (clamped lanes duplicated last edge pad times)
        int padA = (-degA) & 3;
        if (degA > 0 && padA) {
            int last = __builtin_amdgcn_readfirstlane(col[reA - 1]);
            float4 vl = h4[(size_t)last * 16 + fq];
            float fp = (float)padA;
            tA.x = fmaf(-fp, vl.x, tA.x); tA.y = fmaf(-fp, vl.y, tA.y);
            tA.z = fmaf(-fp, vl.z, tA.z); tA.w = fmaf(-fp, vl.w, tA.w);
        }
        int padB = (-degB) & 3;
        if (hasB && degB > 0 && padB) {
            int last = __builtin_amdgcn_readfirstlane(col[reB - 1]);
            float4 vl = h4[(size_t)last * 16 + fq];
            float fp = (float)padB;
            tB.x = fmaf(-fp, vl.x, tB.x); tB.y = fmaf(-fp, vl.y, tB.y);
            tB.z = fmaf(-fp, vl.z, tB.z); tB.w = fmaf(-fp, vl.w, tB.w);
        }

        // self term + normalize
        float4 hsA = h4[(size_t)iA * 16 + fq];
        float invA = 1.0f / (float)(degA + 1);
        tA.x = (tA.x + hsA.x) * invA; tA.y = (tA.y + hsA.y) * invA;
        tA.z = (tA.z + hsA.z) * invA; tA.w = (tA.w + hsA.w) * invA;
        if (hasB) {
            float4 hsB = h4[(size_t)iB * 16 + fq];
            float invB = 1.0f / (float)(degB + 1);
            tB.x = (tB.x + hsB.x) * invB; tB.y = (tB.y + hsB.y) * invB;
            tB.z = (tB.z + hsB.z) * invB; tB.w = (tB.w + hsB.w) * invB;
        }

        // shared-W epilogue: one W-column load per k feeds both nodes
        float oA = bj, oB = bj;
        #pragma unroll
        for (int k = 0; k < D; ++k) {
            float wv = W[k * D + lane];   // L1-resident, reused by A and B
            float cA = ((k & 3) == 0) ? tA.x : ((k & 3) == 1) ? tA.y
                     : ((k & 3) == 2) ? tA.z : tA.w;
            float cB = ((k & 3) == 0) ? tB.x : ((k & 3) == 1) ? tB.y
                     : ((k & 3) == 2) ? tB.z : tB.w;
            int ia = __builtin_amdgcn_readlane(__float_as_int(cA), k >> 2);
            int ib = __builtin_amdgcn_readlane(__float_as_int(cB), k >> 2);
            oA = fmaf(__int_as_float(ia), wv, oA);
            oB = fmaf(__int_as_float(ib), wv, oB);
        }
        if (do_relu) { oA = fmaxf(oA, 0.0f); oB = fmaxf(oB, 0.0f); }
        out[(size_t)iA * D + lane] = oA;
        if (hasB) out[(size_t)iB * D + lane] = oB;
    }
}

extern "C" void kernel_launch(void* const* d_in, const int* in_sizes, int n_in,
                              void* d_out, int out_size, void* d_ws, size_t ws_size,
                              hipStream_t stream) {
    const float* x   = (const float*)d_in[0];
    const int*   src = (const int*)d_in[1];
    const int*   dst = (const int*)d_in[2];
    const float* W0  = (const float*)d_in[3];
    const float* b0  = (const float*)d_in[4];
    const float* W1  = (const float*)d_in[5];
    const float* b1  = (const float*)d_in[6];
    const float* W2  = (const float*)d_in[7];
    const float* b2  = (const float*)d_in[8];
    float* out = (float*)d_out;

    const int N = in_sizes[0] / D;   // 50000
    const int E = in_sizes[1];       // 800000

    const int scan_blocks = (N + 255) / 256;  // 196 (<= 256 required by scan_b)

    // workspace: deg | row_ptr | cursor | blocksums | col | h1 | h2
    char* ws = (char*)d_ws;
    size_t off = 0;
    auto alloc = [&](size_t bytes) -> void* {
        void* p = ws + off;
        off = (off + bytes + 255) & ~(size_t)255;
        return p;
    };
    int*   deg       = (int*)  alloc((size_t)N * sizeof(int));
    int*   row_ptr   = (int*)  alloc((size_t)(N + 1) * sizeof(int));
    int*   cursor    = (int*)  alloc((size_t)N * sizeof(int));
    int*   blocksums = (int*)  alloc((size_t)scan_blocks * sizeof(int));
    int*   col       = (int*)  alloc((size_t)E * sizeof(int));
    float* h1        = (float*)alloc((size_t)N * D * sizeof(float));
    float* h2        = (float*)alloc((size_t)N * D * sizeof(float));

    // --- build CSR (once per call; reused by all 3 layers) ---
    hipMemsetAsync(deg, 0, (size_t)N * sizeof(int), stream);
    const int e4_blocks = (E / 4 + 255) / 256;  // 782
    const int slice_size = (N + 7) / 8;         // 6250
    count_deg_sliced_kernel<<<e4_blocks * 8, 256, 0, stream>>>(dst, deg, E, slice_size);
    scan_a_kernel<<<scan_blocks, 256, 0, stream>>>(deg, row_ptr, blocksums, N);
    scan_b_kernel<<<1, 256, 0, stream>>>(blocksums, row_ptr, scan_blocks, N);
    scan_c_kernel<<<scan_blocks, 256, 0, stream>>>(row_ptr, cursor, blocksums, N);
    fill_csr_sliced_kernel<<<e4_blocks * 8, 256, 0, stream>>>(src, dst, cursor, col, E, slice_size);

    // one node-pair per wave: 25000 pairs -> 6250 blocks x 4 waves
    const int layer_blocks = (N / 2 + 3) / 4;   // 6250

    sage_layer_kernel<<<layer_blocks, 256, 0, stream>>>(x,  row_ptr, col, W0, b0, h1,  N, 1);
    sage_layer_kernel<<<layer_blocks, 256, 0, stream>>>(h1, row_ptr, col, W1, b1, h2,  N, 1);
    sage_layer_kernel<<<layer_blocks, 256, 0, stream>>>(h2, row_ptr, col, W2, b2, out, N, 0);
}